// Round 8
// baseline (191.136 us; speedup 1.0000x reference)
//
#include <hip/hip_runtime.h>
#include <hip/hip_bf16.h>
#include <math.h>

#define B_ 16
#define C_ 64
#define N_ 4096   // 64*64 pixels
#define M_ 1024   // 32*32 pooled keys
#define LOG2E 1.44269504088896340736f

typedef __attribute__((ext_vector_type(8))) short v8s;   // 8 bf16 (4 VGPRs)
typedef __attribute__((ext_vector_type(4))) float v4f;   // 4 fp32 acc

__device__ inline unsigned short f2bf(float f) {
    __hip_bfloat16 h = __float2bfloat16(f);
    return *(unsigned short*)&h;
}
__device__ inline unsigned pack2bf(float a, float b) {
    return (unsigned)f2bf(a) | ((unsigned)f2bf(b) << 16);
}
// single-instruction truncating pack: low16 = hi16(a), high16 = hi16(b)
__device__ inline unsigned packtrunc(float a, float b) {
    return __builtin_amdgcn_perm(__float_as_uint(b), __float_as_uint(a),
                                 0x07060302u);
}
__device__ inline v8s cvt8(float4 a, float4 b) {
    union { v8s v; unsigned u[4]; } r;
    r.u[0] = pack2bf(a.x, a.y);
    r.u[1] = pack2bf(a.z, a.w);
    r.u[2] = pack2bf(b.x, b.y);
    r.u[3] = pack2bf(b.z, b.w);
    return r.v;
}

// ---------------------------------------------------------------------------
// Kernel 1 (round 8): MFMA conv, half-row waves for 2x occupancy (was 1
// block/CU, 4 waves/CU -> now 512 blocks, 8 waves/CU). Wave = half an image
// row (32 px, 2 n-tiles); block = 4 waves = 2 image rows = 1 pooled row.
// theta now stored FP32 (and pre-scaled by log2e so attn can use exp2);
// phi stored FP32; g stays bf16 [ch][key] for the O-MFMA B-operand.
// ---------------------------------------------------------------------------
#define SPSTR2 132   // sPool row stride (floats)

__global__ __launch_bounds__(256) void conv_pool_k(
    const float* __restrict__ x,
    const float* __restrict__ Wt, const float* __restrict__ bt,
    const float* __restrict__ Wp, const float* __restrict__ bp,
    const float* __restrict__ Wg, const float* __restrict__ bg,
    float* __restrict__ thetaF,
    float* __restrict__ phiF,
    unsigned short* __restrict__ gcm)
{
    __shared__ float sPool[40 * SPSTR2];   // ch 0..7 = phi, 8..39 = g

    const int tid  = threadIdx.x;
    const int lane = tid & 63;
    const int wid  = tid >> 6;
    const int l15  = lane & 15;
    const int l4   = lane >> 4;

    const int bx   = blockIdx.x;
    const int b    = bx >> 5;
    const int y0   = (bx & 31) << 1;        // first of 2 image rows
    const int y    = y0 + (wid >> 1);       // this wave's row
    const int half = wid & 1;               // left/right half of the row

    // --- A-fragments: weights, 3 m-tiles x 2 k-halves (bf16, loaded once)
    const float* row0 = (l15 < 8) ? (Wt + l15 * 64) : (Wp + (l15 - 8) * 64);
    const float* row1 = Wg + l15 * 64;
    const float* row2 = Wg + (16 + l15) * 64;
    v8s afrag[3][2];
    #pragma unroll
    for (int kh = 0; kh < 2; ++kh) {
        const int c0 = kh * 32 + l4 * 8;
        afrag[0][kh] = cvt8(*(const float4*)(row0 + c0), *(const float4*)(row0 + c0 + 4));
        afrag[1][kh] = cvt8(*(const float4*)(row1 + c0), *(const float4*)(row1 + c0 + 4));
        afrag[2][kh] = cvt8(*(const float4*)(row2 + c0), *(const float4*)(row2 + c0 + 4));
    }

    v4f acc[2][3];
    {
        float bv[3][4];
        #pragma unroll
        for (int r = 0; r < 4; ++r) {
            const int o = l4 * 4 + r;
            bv[0][r] = (o < 8) ? bt[o] : bp[o - 8];
            bv[1][r] = bg[o];
            bv[2][r] = bg[16 + o];
        }
        #pragma unroll
        for (int nt = 0; nt < 2; ++nt)
            #pragma unroll
            for (int t = 0; t < 3; ++t) {
                v4f a; a[0] = bv[t][0]; a[1] = bv[t][1];
                a[2] = bv[t][2]; a[3] = bv[t][3];
                acc[nt][t] = a;
            }
    }

    const float* xb = x + (size_t)b * C_ * N_ + y * 64;
    #pragma unroll
    for (int nt = 0; nt < 2; ++nt) {
        const int n0 = half * 32 + nt * 16 + l15;
        #pragma unroll
        for (int kh = 0; kh < 2; ++kh) {
            const int cb = kh * 32 + l4 * 8;
            float f[8];
            #pragma unroll
            for (int j = 0; j < 8; ++j) f[j] = xb[(size_t)(cb + j) * N_ + n0];
            union { v8s v; unsigned u[4]; } bf;
            #pragma unroll
            for (int j = 0; j < 4; ++j) bf.u[j] = pack2bf(f[2*j], f[2*j+1]);
            #pragma unroll
            for (int t = 0; t < 3; ++t)
                acc[nt][t] = __builtin_amdgcn_mfma_f32_16x16x32_bf16(
                    afrag[t][kh], bf.v, acc[nt][t], 0, 0, 0);
        }
    }

    // --- theta: fp32, pre-scaled by log2e, layout [n][8] (rows 0..7 of tile0)
    #pragma unroll
    for (int nt = 0; nt < 2; ++nt) {
        if (l4 < 2) {
            const int n = y * 64 + half * 32 + nt * 16 + l15;
            float4 v = make_float4(acc[nt][0][0] * LOG2E, acc[nt][0][1] * LOG2E,
                                   acc[nt][0][2] * LOG2E, acc[nt][0][3] * LOG2E);
            *(float4*)(thetaF + ((size_t)b * N_ + n) * 8 + l4 * 4) = v;
        }
    }

    // --- stage phi/g to LDS for pooling ([ch][rowbit*64 + x])
    #pragma unroll
    for (int nt = 0; nt < 2; ++nt) {
        const int px = (wid >> 1) * 64 + half * 32 + nt * 16 + l15;
        if (l4 >= 2) {
            #pragma unroll
            for (int r = 0; r < 4; ++r)
                sPool[((l4 - 2) * 4 + r) * SPSTR2 + px] = acc[nt][0][r];
        }
        #pragma unroll
        for (int r = 0; r < 4; ++r) {
            sPool[(8  + l4 * 4 + r) * SPSTR2 + px] = acc[nt][1][r];
            sPool[(24 + l4 * 4 + r) * SPSTR2 + px] = acc[nt][2][r];
        }
    }
    __syncthreads();

    // --- 2x2 maxpool + store: 40 ch x 32 pooled px per block
    {
        const int pc = tid & 31, cgrp = tid >> 5;   // 8 groups x 5 channels
        const int mg = (bx & 31) * 32 + pc;
        #pragma unroll
        for (int i = 0; i < 5; ++i) {
            const int ch = cgrp * 5 + i;
            const float* sp = sPool + ch * SPSTR2;
            const float v = fmaxf(fmaxf(sp[2*pc], sp[2*pc + 1]),
                                  fmaxf(sp[64 + 2*pc], sp[64 + 2*pc + 1]));
            if (ch < 8) phiF[((size_t)b * M_ + mg) * 8 + ch] = v;
            else        gcm[((size_t)(b * 32 + ch - 8)) * M_ + mg] = f2bf(v);
        }
    }
}

// ---------------------------------------------------------------------------
// Kernel 2 (round 8): barrier-free attention main loop. The r4-r7 skeleton
// (S-MFMA -> exp -> LDS round-trip -> O-MFMA, barriers every 256 keys) was
// stuck at ~40us across 3 structural variants. New skeleton:
//   - S computed by VALU fp32 dot DIRECTLY in O-MFMA A-layout: lane
//     (q=l15, keys l4*8+j) -> no S-MFMA, no sP, no transposition.
//   - phi fp32 read straight from cache (32KB/batch -> L1/L2 resident).
//   - g bf16 b128 B-frags straight from L2 (64KB/batch).
//   - exp2 (log2e folded into theta at conv) -> one v_exp each.
//   - NO LDS, NO barriers until the epilogue transpose.
// MFMA layouts (measured m89/m91): A[m=l15][k=l4*8+j], B[k=l4*8+j][n=l15],
// C/D: col(n)=l15, row(m)=l4*4+reg.
// ---------------------------------------------------------------------------
#define SOSTR  36    // sO row stride (floats): 144 B, 16B-aligned

__global__ __launch_bounds__(256) void attn_k(
    const float* __restrict__ x,
    const float* __restrict__ thetaF,
    const float* __restrict__ phiF,
    const unsigned short* __restrict__ gcm,
    const float* __restrict__ Wo, const float* __restrict__ bo,
    const float* __restrict__ gammap,
    float* __restrict__ out)
{
    __shared__ float sO[64][SOSTR];              // 9.2 KB [q][c] epilogue only

    const int tid  = threadIdx.x;
    const int lane = tid & 63;
    const int wid  = tid >> 6;
    const int l15  = lane & 15;
    const int l4   = lane >> 4;

    const int b  = blockIdx.x >> 6;          // 64 blocks per batch
    const int q0 = (blockIdx.x & 63) << 6;   // 64 queries per block
    const int qw = q0 + wid * 16;            // this wave's 16 queries

    // per-lane theta (fp32, log2e-scaled): 8 channels of query q = l15
    float t0,t1,t2,t3,t4,t5,t6,t7;
    {
        const float4* tp = (const float4*)(thetaF + ((size_t)b * N_ + qw + l15) * 8);
        const float4 a = tp[0], c = tp[1];
        t0=a.x; t1=a.y; t2=a.z; t3=a.w; t4=c.x; t5=c.y; t6=c.z; t7=c.w;
    }

    v4f accO[2];
    { v4f z = {}; accO[0] = z; accO[1] = z; }
    float lsum = 0.f;

    const float*          phb = phiF + (size_t)b * M_ * 8;
    const unsigned short* gb  = gcm  + (size_t)(b * 32) * M_;

    for (int cc = 0; cc < 32; ++cc) {        // 32 chunks of 32 keys
        const int kb = cc * 32 + l4 * 8;     // this lane's 8 keys
        float e[8];
        #pragma unroll
        for (int j = 0; j < 8; ++j) {
            const float4* pr = (const float4*)(phb + (size_t)(kb + j) * 8);
            const float4 pa = pr[0], pb = pr[1];
            float s;
            s = t0 * pa.x;
            s = fmaf(t1, pa.y, s);
            s = fmaf(t2, pa.z, s);
            s = fmaf(t3, pa.w, s);
            s = fmaf(t4, pb.x, s);
            s = fmaf(t5, pb.y, s);
            s = fmaf(t6, pb.z, s);
            s = fmaf(t7, pb.w, s);
            e[j] = exp2f(s);                 // theta pre-scaled by log2e
            lsum += e[j];
        }
        union { v8s v; unsigned u[4]; } ap;
        #pragma unroll
        for (int j = 0; j < 4; ++j) ap.u[j] = packtrunc(e[2*j], e[2*j+1]);

        const v8s bg0 = *(const v8s*)(gb + (size_t)l15        * M_ + kb);
        const v8s bg1 = *(const v8s*)(gb + (size_t)(16 + l15) * M_ + kb);
        accO[0] = __builtin_amdgcn_mfma_f32_16x16x32_bf16(ap.v, bg0, accO[0], 0, 0, 0);
        accO[1] = __builtin_amdgcn_mfma_f32_16x16x32_bf16(ap.v, bg1, accO[1], 0, 0, 0);
    }

    // softmax denominator: lane has partial for q=l15 over keys l4*8+j (+32cc)
    // -> sum the 4 l4-groups
    lsum += __shfl_xor(lsum, 16);
    lsum += __shfl_xor(lsum, 32);
    const float rl_all = 1.0f / lsum;        // valid for q = l15, all lanes

    // accO C-layout rows are q = l4*4 + r -> fetch matching denominators
    float rlq[4];
    #pragma unroll
    for (int r = 0; r < 4; ++r) rlq[r] = __shfl(rl_all, l4 * 4 + r);

    // write normalized O to LDS [q][c] (16B-aligned rows for b128 reads)
    #pragma unroll
    for (int ct = 0; ct < 2; ++ct)
        #pragma unroll
        for (int r = 0; r < 4; ++r)
            sO[wid * 16 + l4 * 4 + r][ct * 16 + l15] = accO[ct][r] * rlq[r];
    __syncthreads();

    // epilogue: out = gamma*(Wo . O + bo) + x. 256 thr = 64 q x 4 oc-quarters.
    {
        const int qq   = tid & 63;
        const int quad = tid >> 6;          // oc 16*quad .. 16*quad+15
        const int n    = q0 + qq;
        float4 col4[8];
        const float4* so4 = (const float4*)&sO[qq][0];
        #pragma unroll
        for (int j = 0; j < 8; ++j) col4[j] = so4[j];
        const float* col = (const float*)col4;
        const float gamma = *gammap;
        const float* xb = x   + ((size_t)(b * 64 + quad * 16)) * N_ + n;
        float*       ob = out + ((size_t)(b * 64 + quad * 16)) * N_ + n;
        #pragma unroll
        for (int j = 0; j < 16; ++j) {
            const int oc = quad * 16 + j;
            const float* w = Wo + oc * 32;   // wave-uniform -> s_load
            float r = 0.f;
            #pragma unroll
            for (int c = 0; c < 32; ++c) r = fmaf(w[c], col[c], r);
            ob[(size_t)j * N_] = gamma * (r + bo[oc]) + xb[(size_t)j * N_];
        }
    }
}

// ---------------------------------------------------------------------------
extern "C" void kernel_launch(void* const* d_in, const int* in_sizes, int n_in,
                              void* d_out, int out_size, void* d_ws, size_t ws_size,
                              hipStream_t stream) {
    const float* x  = (const float*)d_in[0];
    const float* Wt = (const float*)d_in[1];
    const float* bt = (const float*)d_in[2];
    const float* Wp = (const float*)d_in[3];
    const float* bp = (const float*)d_in[4];
    const float* Wg = (const float*)d_in[5];
    const float* bg = (const float*)d_in[6];
    const float* Wo = (const float*)d_in[7];
    const float* bo = (const float*)d_in[8];
    const float* gm = (const float*)d_in[9];
    float* out = (float*)d_out;

    // workspace: thetaF fp32 [16][4096][8] | phiF fp32 [16][1024][8]
    //          | gcm bf16 [16*32][1024]   (3.5 MB total)
    float* thetaF = (float*)d_ws;
    float* phiF   = thetaF + (size_t)B_ * N_ * 8;
    unsigned short* gcm = (unsigned short*)(phiF + (size_t)B_ * M_ * 8);

    hipLaunchKernelGGL(conv_pool_k, dim3(512), dim3(256), 0, stream,
                       x, Wt, bt, Wp, bp, Wg, bg, thetaF, phiF, gcm);
    hipLaunchKernelGGL(attn_k, dim3(1024), dim3(256), 0, stream,
                       x, thetaF, phiF, gcm, Wo, bo, gm, out);
}

// Round 9
// 136.457 us; speedup vs baseline: 1.4007x; 1.4007x over previous
//
#include <hip/hip_runtime.h>
#include <hip/hip_bf16.h>
#include <math.h>

#define B_ 16
#define C_ 64
#define N_ 4096   // 64*64 pixels
#define M_ 1024   // 32*32 pooled keys
#define LOG2E 1.44269504088896340736f

typedef __attribute__((ext_vector_type(8))) short v8s;   // 8 bf16 (4 VGPRs)
typedef __attribute__((ext_vector_type(4))) float v4f;   // 4 fp32 acc

__device__ inline unsigned short f2bf(float f) {
    __hip_bfloat16 h = __float2bfloat16(f);
    return *(unsigned short*)&h;
}
__device__ inline unsigned pack2bf(float a, float b) {
    return (unsigned)f2bf(a) | ((unsigned)f2bf(b) << 16);
}
// single-instruction truncating pack: low16 = hi16(a), high16 = hi16(b)
__device__ inline unsigned packtrunc(float a, float b) {
    return __builtin_amdgcn_perm(__float_as_uint(b), __float_as_uint(a),
                                 0x07060302u);
}
__device__ inline v8s cvt8(float4 a, float4 b) {
    union { v8s v; unsigned u[4]; } r;
    r.u[0] = pack2bf(a.x, a.y);
    r.u[1] = pack2bf(a.z, a.w);
    r.u[2] = pack2bf(b.x, b.y);
    r.u[3] = pack2bf(b.z, b.w);
    return r.v;
}

// ---------------------------------------------------------------------------
// Kernel 1: MFMA conv, half-row waves (r8 structure: 512 blocks, 2 blocks/CU,
// 8 waves/CU), outputs in the r7 bf16 attn layouts. theta is pre-scaled by
// log2e so attn uses exp2 directly.
// MFMA layouts (measured m89/m91): A[m=l15][k=l4*8+j], B[k=l4*8+j][n=l15],
// C/D: col(n)=l15, row(m)=l4*4+reg.
// ---------------------------------------------------------------------------
#define SPSTR2 132   // sPool row stride (floats)

__global__ __launch_bounds__(256) void conv_pool_k(
    const float* __restrict__ x,
    const float* __restrict__ Wt, const float* __restrict__ bt,
    const float* __restrict__ Wp, const float* __restrict__ bp,
    const float* __restrict__ Wg, const float* __restrict__ bg,
    unsigned short* __restrict__ thetaT,
    unsigned short* __restrict__ phiT,
    unsigned short* __restrict__ gcm)
{
    __shared__ float sPool[40 * SPSTR2];   // ch 0..7 = phi, 8..39 = g

    const int tid  = threadIdx.x;
    const int lane = tid & 63;
    const int wid  = tid >> 6;
    const int l15  = lane & 15;
    const int l4   = lane >> 4;

    const int bx   = blockIdx.x;
    const int b    = bx >> 5;
    const int y0   = (bx & 31) << 1;        // first of 2 image rows
    const int y    = y0 + (wid >> 1);       // this wave's row
    const int half = wid & 1;               // left/right half of the row

    // --- A-fragments: weights, 3 m-tiles x 2 k-halves (bf16, loaded once)
    const float* row0 = (l15 < 8) ? (Wt + l15 * 64) : (Wp + (l15 - 8) * 64);
    const float* row1 = Wg + l15 * 64;
    const float* row2 = Wg + (16 + l15) * 64;
    v8s afrag[3][2];
    #pragma unroll
    for (int kh = 0; kh < 2; ++kh) {
        const int c0 = kh * 32 + l4 * 8;
        afrag[0][kh] = cvt8(*(const float4*)(row0 + c0), *(const float4*)(row0 + c0 + 4));
        afrag[1][kh] = cvt8(*(const float4*)(row1 + c0), *(const float4*)(row1 + c0 + 4));
        afrag[2][kh] = cvt8(*(const float4*)(row2 + c0), *(const float4*)(row2 + c0 + 4));
    }

    v4f acc[2][3];
    {
        float bv[3][4];
        #pragma unroll
        for (int r = 0; r < 4; ++r) {
            const int o = l4 * 4 + r;
            bv[0][r] = (o < 8) ? bt[o] : bp[o - 8];
            bv[1][r] = bg[o];
            bv[2][r] = bg[16 + o];
        }
        #pragma unroll
        for (int nt = 0; nt < 2; ++nt)
            #pragma unroll
            for (int t = 0; t < 3; ++t) {
                v4f a; a[0] = bv[t][0]; a[1] = bv[t][1];
                a[2] = bv[t][2]; a[3] = bv[t][3];
                acc[nt][t] = a;
            }
    }

    const float* xb = x + (size_t)b * C_ * N_ + y * 64;
    #pragma unroll
    for (int nt = 0; nt < 2; ++nt) {
        const int n0 = half * 32 + nt * 16 + l15;
        #pragma unroll
        for (int kh = 0; kh < 2; ++kh) {
            const int cb = kh * 32 + l4 * 8;
            float f[8];
            #pragma unroll
            for (int j = 0; j < 8; ++j) f[j] = xb[(size_t)(cb + j) * N_ + n0];
            union { v8s v; unsigned u[4]; } bf;
            #pragma unroll
            for (int j = 0; j < 4; ++j) bf.u[j] = pack2bf(f[2*j], f[2*j+1]);
            #pragma unroll
            for (int t = 0; t < 3; ++t)
                acc[nt][t] = __builtin_amdgcn_mfma_f32_16x16x32_bf16(
                    afrag[t][kh], bf.v, acc[nt][t], 0, 0, 0);
        }
    }

    // --- theta: bf16 [n][8], PRE-SCALED by log2e (rows 0..7 of tile0)
    #pragma unroll
    for (int nt = 0; nt < 2; ++nt) {
        if (l4 < 2) {
            const int n = y * 64 + half * 32 + nt * 16 + l15;
            const unsigned lo = pack2bf(acc[nt][0][0] * LOG2E, acc[nt][0][1] * LOG2E);
            const unsigned hi = pack2bf(acc[nt][0][2] * LOG2E, acc[nt][0][3] * LOG2E);
            *(uint2*)(thetaT + ((size_t)b * N_ + n) * 8 + l4 * 4) = make_uint2(lo, hi);
        }
    }

    // --- stage phi/g to LDS for pooling ([ch][rowbit*64 + x])
    #pragma unroll
    for (int nt = 0; nt < 2; ++nt) {
        const int px = (wid >> 1) * 64 + half * 32 + nt * 16 + l15;
        if (l4 >= 2) {
            #pragma unroll
            for (int r = 0; r < 4; ++r)
                sPool[((l4 - 2) * 4 + r) * SPSTR2 + px] = acc[nt][0][r];
        }
        #pragma unroll
        for (int r = 0; r < 4; ++r) {
            sPool[(8  + l4 * 4 + r) * SPSTR2 + px] = acc[nt][1][r];
            sPool[(24 + l4 * 4 + r) * SPSTR2 + px] = acc[nt][2][r];
        }
    }
    __syncthreads();

    // --- 2x2 maxpool + store: 40 ch x 32 pooled px per block
    {
        const int pc = tid & 31, cgrp = tid >> 5;   // 8 groups x 5 channels
        const int mg = (bx & 31) * 32 + pc;
        #pragma unroll
        for (int i = 0; i < 5; ++i) {
            const int ch = cgrp * 5 + i;
            const float* sp = sPool + ch * SPSTR2;
            const float v = fmaxf(fmaxf(sp[2*pc], sp[2*pc + 1]),
                                  fmaxf(sp[64 + 2*pc], sp[64 + 2*pc + 1]));
            if (ch < 8) phiT[((size_t)b * M_ + mg) * 8 + ch] = f2bf(v);
            else        gcm[((size_t)(b * 32 + ch - 8)) * M_ + mg] = f2bf(v);
        }
    }
}

// ---------------------------------------------------------------------------
// Kernel 2 (round 9): r7 attention skeleton (best known, ~40us) + register
// prefetch of the next tile WITHOUT a launch-bounds cap. r5 taught: the
// spill came from __launch_bounds__(256,4) squeezing to 64 VGPR, not from
// prefetch. Occupancy here is LDS-bound (40KB -> 4 blocks/CU = 16 waves/CU),
// which tolerates up to 128 VGPR; base ~70 + ~20 prefetch stays under it.
// exp2f (theta pre-scaled by log2e) replaces __expf.
// MFMA layouts (measured m89/m91): A[m=l15][k=l4*8+j], B[k=l4*8+j][n=l15],
// C/D: col(n)=l15, row(m)=l4*4+reg.
// ---------------------------------------------------------------------------
#define GPAD   264   // sgT row stride (shorts): 2-way banks (free)
#define PROW   40    // sP row stride (shorts): 80 B, 16B-aligned
#define SOSTR  36    // sO row stride (floats): 144 B, 16B-aligned

__global__ __launch_bounds__(256) void attn_k(
    const float* __restrict__ x,
    const unsigned short* __restrict__ thetaT,
    const unsigned short* __restrict__ phiT,
    const unsigned short* __restrict__ gcm,
    const float* __restrict__ Wo, const float* __restrict__ bo,
    const float* __restrict__ gammap,
    float* __restrict__ out)
{
    __shared__ unsigned short sphi[2][128][8];     // 4 KB   even/odd key split
    __shared__ unsigned short sgT[32][GPAD];       // 16.5 KB [c][m-chunk]
    __shared__ unsigned short sP[4][2][16][PROW];  // 10.2 KB per-wave, 2 slabs
    __shared__ float sO[64][SOSTR];                // 9.2 KB  [q][c] epilogue

    const int tid  = threadIdx.x;
    const int lane = tid & 63;
    const int wid  = tid >> 6;
    const int l15  = lane & 15;
    const int l4   = lane >> 4;

    const int b  = blockIdx.x >> 6;          // 64 blocks per batch
    const int q0 = (blockIdx.x & 63) << 6;   // 64 queries per block
    const int qw = q0 + wid * 16;            // this wave's 16 queries

    // phase-stagger across waves/blocks (exp-sum is order-invariant)
    const int rot = ((wid + blockIdx.x) << 1) & 7;

    // theta A-fragment (K=8 real, rest zero): lanes 16..63 zero
    v8s aT;
    {
        v8s z = {};
        aT = z;
        if (l4 == 0)
            aT = *(const v8s*)(thetaT + ((size_t)b * N_ + qw + l15) * 8);
    }

    v4f accO[2];
    { v4f z = {}; accO[0] = z; accO[1] = z; }
    float lsum[4] = {0.f, 0.f, 0.f, 0.f};
    const v4f zf = {};

    const unsigned short* phb = phiT + (size_t)b * M_ * 8;
    const unsigned short* gb  = gcm  + (size_t)(b * 32) * M_;
    const int grow = tid >> 3, gch = tid & 7;

    // prefetch tile 0 into registers (no barrier dependency yet)
    uint4 pf_phi = *(const uint4*)(phb + (size_t)tid * 8);
    uint4 pf_g[4];
    {
        const uint4* gs = (const uint4*)(gb + (size_t)grow * M_ + gch * 32);
        pf_g[0] = gs[0]; pf_g[1] = gs[1]; pf_g[2] = gs[2]; pf_g[3] = gs[3];
    }

    for (int t = 0; t < 4; ++t) {            // 4 key tiles of 256
        // stage the prefetched tile to LDS
        *(uint4*)&sphi[tid & 1][tid >> 1][0] = pf_phi;
        {
            uint4* gd = (uint4*)&sgT[grow][gch * 32];
            gd[0] = pf_g[0]; gd[1] = pf_g[1]; gd[2] = pf_g[2]; gd[3] = pf_g[3];
        }
        __syncthreads();

        // issue next tile's loads now — in flight during this tile's compute
        if (t < 3) {
            pf_phi = *(const uint4*)(phb + (size_t)((t + 1) * 256 + tid) * 8);
            const uint4* gs = (const uint4*)(gb + (size_t)grow * M_ + (t + 1) * 256 + gch * 32);
            pf_g[0] = gs[0]; pf_g[1] = gs[1]; pf_g[2] = gs[2]; pf_g[3] = gs[3];
        }

        for (int pp = 0; pp < 4; ++pp) {     // 4 pairs of 32-key chunks
            const int ca = (rot + 2 * pp) & 7;   // even chunk id
            const int cb = ca + 1;               // odd partner

            // --- S phase for both chunks (4 independent MFMAs)
            v8s bphA0, bphA1, bphB0, bphB1;
            { v8s z = {}; bphA0 = z; bphA1 = z; bphB0 = z; bphB1 = z; }
            if (l4 == 0) {
                bphA0 = *(const v8s*)&sphi[0][ca * 16 + l15][0];
                bphA1 = *(const v8s*)&sphi[1][ca * 16 + l15][0];
                bphB0 = *(const v8s*)&sphi[0][cb * 16 + l15][0];
                bphB1 = *(const v8s*)&sphi[1][cb * 16 + l15][0];
            }
            v4f sA0 = __builtin_amdgcn_mfma_f32_16x16x32_bf16(aT, bphA0, zf, 0, 0, 0);
            v4f sA1 = __builtin_amdgcn_mfma_f32_16x16x32_bf16(aT, bphA1, zf, 0, 0, 0);
            v4f sB0 = __builtin_amdgcn_mfma_f32_16x16x32_bf16(aT, bphB0, zf, 0, 0, 0);
            v4f sB1 = __builtin_amdgcn_mfma_f32_16x16x32_bf16(aT, bphB1, zf, 0, 0, 0);

            // --- bg reads: independent of S/exp, issue early
            v8s bgA0 = *(const v8s*)&sgT[l15     ][ca * 32 + l4 * 8];
            v8s bgA1 = *(const v8s*)&sgT[16 + l15][ca * 32 + l4 * 8];
            v8s bgB0 = *(const v8s*)&sgT[l15     ][cb * 32 + l4 * 8];
            v8s bgB1 = *(const v8s*)&sgT[16 + l15][cb * 32 + l4 * 8];

            // --- exp2 + 1-instr truncating pack + lsum
            #pragma unroll
            for (int r = 0; r < 4; ++r) {
                const float a0 = exp2f(sA0[r]);   // key ca*32 + 2*l15
                const float a1 = exp2f(sA1[r]);   // key ca*32 + 2*l15+1
                const float b0 = exp2f(sB0[r]);
                const float b1 = exp2f(sB1[r]);
                lsum[r] += (a0 + a1) + (b0 + b1);
                *(unsigned*)&sP[wid][0][l4 * 4 + r][2 * l15] = packtrunc(a0, a1);
                *(unsigned*)&sP[wid][1][l4 * 4 + r][2 * l15] = packtrunc(b0, b1);
            }

            // --- O phase for both chunks
            v8s apA = *(const v8s*)&sP[wid][0][l15][l4 * 8];
            v8s apB = *(const v8s*)&sP[wid][1][l15][l4 * 8];
            accO[0] = __builtin_amdgcn_mfma_f32_16x16x32_bf16(apA, bgA0, accO[0], 0, 0, 0);
            accO[1] = __builtin_amdgcn_mfma_f32_16x16x32_bf16(apA, bgA1, accO[1], 0, 0, 0);
            accO[0] = __builtin_amdgcn_mfma_f32_16x16x32_bf16(apB, bgB0, accO[0], 0, 0, 0);
            accO[1] = __builtin_amdgcn_mfma_f32_16x16x32_bf16(apB, bgB1, accO[1], 0, 0, 0);
        }
        __syncthreads();   // before next tile overwrites sphi/sgT
    }

    // softmax denominators: reduce across the 16 key-columns (lane&15)
    float rl[4];
    #pragma unroll
    for (int r = 0; r < 4; ++r) {
        float v = lsum[r];
        v += __shfl_xor(v, 1);
        v += __shfl_xor(v, 2);
        v += __shfl_xor(v, 4);
        v += __shfl_xor(v, 8);
        rl[r] = 1.0f / v;
    }

    // write normalized O to LDS [q][c] (16B-aligned rows for b128 reads)
    #pragma unroll
    for (int ct = 0; ct < 2; ++ct)
        #pragma unroll
        for (int r = 0; r < 4; ++r)
            sO[wid * 16 + l4 * 4 + r][ct * 16 + l15] = accO[ct][r] * rl[r];
    __syncthreads();

    // epilogue: out = gamma*(Wo . O + bo) + x. 256 thr = 64 q x 4 oc-quarters.
    {
        const int qq   = tid & 63;
        const int quad = tid >> 6;          // oc 16*quad .. 16*quad+15
        const int n    = q0 + qq;
        float4 col4[8];
        const float4* so4 = (const float4*)&sO[qq][0];
        #pragma unroll
        for (int j = 0; j < 8; ++j) col4[j] = so4[j];
        const float* col = (const float*)col4;
        const float gamma = *gammap;
        const float* xb = x   + ((size_t)(b * 64 + quad * 16)) * N_ + n;
        float*       ob = out + ((size_t)(b * 64 + quad * 16)) * N_ + n;
        #pragma unroll
        for (int j = 0; j < 16; ++j) {
            const int oc = quad * 16 + j;
            const float* w = Wo + oc * 32;   // wave-uniform -> s_load
            float r = 0.f;
            #pragma unroll
            for (int c = 0; c < 32; ++c) r = fmaf(w[c], col[c], r);
            ob[(size_t)j * N_] = gamma * (r + bo[oc]) + xb[(size_t)j * N_];
        }
    }
}

// ---------------------------------------------------------------------------
extern "C" void kernel_launch(void* const* d_in, const int* in_sizes, int n_in,
                              void* d_out, int out_size, void* d_ws, size_t ws_size,
                              hipStream_t stream) {
    const float* x  = (const float*)d_in[0];
    const float* Wt = (const float*)d_in[1];
    const float* bt = (const float*)d_in[2];
    const float* Wp = (const float*)d_in[3];
    const float* bp = (const float*)d_in[4];
    const float* Wg = (const float*)d_in[5];
    const float* bg = (const float*)d_in[6];
    const float* Wo = (const float*)d_in[7];
    const float* bo = (const float*)d_in[8];
    const float* gm = (const float*)d_in[9];
    float* out = (float*)d_out;

    // workspace (bf16): thetaT [16][4096][8] | phiT [16][1024][8] | gcm [16][32][1024]
    unsigned short* thetaT = (unsigned short*)d_ws;
    unsigned short* phiT   = thetaT + (size_t)B_ * N_ * 8;
    unsigned short* gcm    = phiT   + (size_t)B_ * M_ * 8;

    hipLaunchKernelGGL(conv_pool_k, dim3(512), dim3(256), 0, stream,
                       x, Wt, bt, Wp, bp, Wg, bg, thetaT, phiT, gcm);
    hipLaunchKernelGGL(attn_k, dim3(1024), dim3(256), 0, stream,
                       x, thetaT, phiT, gcm, Wo, bo, gm, out);
}